// Round 3
// baseline (403.131 us; speedup 1.0000x reference)
//
#include <hip/hip_runtime.h>

typedef unsigned int  uint;
typedef unsigned short ushort;

#define N_PTS  1048576
#define BLOCK  512
#define WAVES  8
#define NPT    2
#define CHUNK  (WAVES * NPT * 16)     // 256 points per block-iteration
#define NCHUNK (N_PTS / CHUNK)        // 4096
#define GRID   1024                   // 4 blocks/CU resident (LDS 128/160 KB)

static_assert(N_PTS % CHUNK == 0, "chunking");
static_assert(NCHUNK % GRID == 0, "grid stride");

typedef __attribute__((ext_vector_type(8))) __bf16  bf16x8;
typedef __attribute__((ext_vector_type(2))) __bf16  bf16x2;
typedef __attribute__((ext_vector_type(4))) float   f32x4;

struct Params {
    const float* emb[3];
    const float* views;
    const float* mask[3];
    const float* w[21];
    float* out;
};

// Pre-arranged bf16 A-fragment weight blob, written by prep_weights each call.
__device__ uint g_wbuf[3 * 9216];

// per-branch weight blob layout (u16 offsets into g_wbuf viewed as ushort*)
#define OFF_S0 0
#define OFF_S1 2048
#define OFF_S2 6144
#define OFF_C0 7168
#define OFF_C1 9216
#define OFF_C2 13312
#define OFF_C3 17408
#define BR_SZ  18432

// f32 pair -> packed bf16x2 (compiler emits v_cvt_pk_bf16_f32, RNE)
__device__ __forceinline__ uint cvt2(float a, float b) {
    bf16x2 v = {(__bf16)a, (__bf16)b};
    return __builtin_bit_cast(uint, v);
}

__device__ __forceinline__ f32x4 MFMA(bf16x8 a, bf16x8 b, f32x4 c) {
    return __builtin_amdgcn_mfma_f32_16x16x32_bf16(a, b, c, 0, 0, 0);
}

__device__ __forceinline__ float fast_rcp(float x) { return __builtin_amdgcn_rcpf(x); }

// Swizzled pointer into a 16x64-bf16 activation tile (2048 B, row stride 128 B).
__device__ __forceinline__ ushort* actp(ushort* buf, int c, int f) {
    int byte = (c << 7) + (f << 1);
    byte ^= (c & 7) << 4;
    return (ushort*)((char*)buf + byte);
}

// weight element fetch with layer-specific remapping (see R1 notes).
__device__ __forceinline__ float wval(int kind, const float* W, int k, int m) {
    switch (kind) {
        default:
        case 0: return W[k * 64 + m];
        case 1: return W[k * 17 + (m == 0 ? 0 : m + 1)];
        case 2: { int r = (k >= 1 && k <= 15) ? (k + 2) : ((k >= 16 && k <= 18) ? (k - 16) : -1);
                  return (r < 0) ? 0.f : W[r * 64 + m]; }
        case 3: { int r = (k >= 1 && k <= 15) ? (k - 1) : -1;
                  return (r < 0) ? 0.f : W[r * 64 + m]; }
        case 4: return (m < 3) ? W[k * 3 + m] : 0.f;
    }
}

// ------------------- prologue: arrange weights as A-fragments -------------------
__global__ void prep_weights(Params P) {
    const int idx = blockIdx.x * 256 + threadIdx.x;   // 0 .. 27647
    const int br  = idx / 9216;
    const int rem = idx - br * 9216;
    int L, q;
    if      (rem < 1024) { L = 0; q = rem;        }
    else if (rem < 3072) { L = 1; q = rem - 1024; }
    else if (rem < 3584) { L = 2; q = rem - 3072; }
    else if (rem < 4608) { L = 3; q = rem - 3584; }
    else if (rem < 6656) { L = 4; q = rem - 4608; }
    else if (rem < 8704) { L = 5; q = rem - 6656; }
    else                 { L = 6; q = rem - 8704; }
    const float* W   = P.w[br * 7 + L];
    const int kk_n   = (L == 0 || L == 3) ? 1 : 2;
    const int kind   = (L == 2) ? 1 : (L == 3) ? (br == 0 ? 2 : 3) : (L == 6) ? 4 : 0;
    const int E  = q * 2;
    const int b  = E >> 9;
    const int ln = (E >> 3) & 63;
    const int e  = E & 7;
    const int mt = b / kk_n;
    const int kk = b - mt * kk_n;
    const int m  = mt * 16 + (ln & 15);
    const int k  = kk * 32 + (ln >> 4) * 8 + e;
    g_wbuf[idx] = cvt2(wval(kind, W, k, m), wval(kind, W, k + 1, m));
}

// hidden 64->64 layer with relu, NPT tiles; weights read straight from global blob
__device__ __forceinline__ void layer_h64(const ushort* lw, int lane,
                                          ushort* const (&rd0)[NPT],
                                          ushort* const (&rd1)[NPT],
                                          ushort* const (&wr)[NPT][4]) {
    bf16x8 wf[8];
#pragma unroll
    for (int b = 0; b < 8; ++b) wf[b] = *(const bf16x8*)(lw + b * 512 + lane * 8);
#pragma unroll
    for (int t = 0; t < NPT; ++t) {
        const bf16x8 i0 = *(const bf16x8*)rd0[t];
        const bf16x8 i1 = *(const bf16x8*)rd1[t];
        f32x4 acc[4];
#pragma unroll
        for (int mt = 0; mt < 4; ++mt) {
            acc[mt] = (f32x4){0.f, 0.f, 0.f, 0.f};
            acc[mt] = MFMA(wf[mt * 2 + 0], i0, acc[mt]);
            acc[mt] = MFMA(wf[mt * 2 + 1], i1, acc[mt]);
        }
#pragma unroll
        for (int mt = 0; mt < 4; ++mt) {
            uint2 o;
            o.x = cvt2(fmaxf(acc[mt][0], 0.f), fmaxf(acc[mt][1], 0.f));
            o.y = cvt2(fmaxf(acc[mt][2], 0.f), fmaxf(acc[mt][3], 0.f));
            *(uint2*)wr[t][mt] = o;
        }
    }
}

__global__ __launch_bounds__(BLOCK, 8) void nerf_main(Params P) {
    __shared__ __align__(16) ushort lds_act[WAVES][NPT][1024]; // 32 KB act tiles only

    const int tid  = threadIdx.x;
    const int wave = tid >> 6;
    const int lane = tid & 63;
    const int c = lane & 15;   // point within tile
    const int g = lane >> 4;   // lane group
    const ushort* gw = (const ushort*)g_wbuf;

    // hoisted swizzled LDS addresses (loop-invariant per lane)
    ushort* rd0[NPT]; ushort* rd1[NPT]; ushort* wr[NPT][4];
#pragma unroll
    for (int t = 0; t < NPT; ++t) {
        ushort* base = lds_act[wave][t];
        rd0[t] = actp(base, c, g * 8);
        rd1[t] = actp(base, c, 32 + g * 8);
#pragma unroll
        for (int mt = 0; mt < 4; ++mt) wr[t][mt] = actp(base, c, mt * 16 + g * 4);
    }

#pragma unroll 1
    for (int ch = blockIdx.x; ch < NCHUNK; ch += gridDim.x) {
        const int p0 = ch * CHUNK + wave * (NPT * 16);

        float stot[NPT], car[NPT], cag[NPT], cab[NPT];
#pragma unroll
        for (int t = 0; t < NPT; ++t) { stot[t] = 0.f; car[t] = 0.f; cag[t] = 0.f; cab[t] = 0.f; }

#pragma unroll 1
        for (int br = 0; br < 3; ++br) {
            const ushort* lw  = gw + br * BR_SZ;
            const float* emb  = P.emb[br];
            const float* msk  = P.mask[br];
            float sig_pre[NPT], rp[NPT], gp[NPT], bp[NPT];

            // ---- sigma L0 : emb(32) -> 64, relu
            {
                bf16x8 wf[4];
#pragma unroll
                for (int b = 0; b < 4; ++b)
                    wf[b] = *(const bf16x8*)(lw + OFF_S0 + b * 512 + lane * 8);
#pragma unroll
                for (int t = 0; t < NPT; ++t) {
                    const float* ep = emb + (size_t)(p0 + t * 16 + c) * 32 + g * 8;
                    const float4 ea = *(const float4*)ep;
                    const float4 eb = *(const float4*)(ep + 4);
                    uint4 iv;
                    iv.x = cvt2(ea.x, ea.y); iv.y = cvt2(ea.z, ea.w);
                    iv.z = cvt2(eb.x, eb.y); iv.w = cvt2(eb.z, eb.w);
                    const bf16x8 inf = __builtin_bit_cast(bf16x8, iv);
                    f32x4 acc[4];
#pragma unroll
                    for (int mt = 0; mt < 4; ++mt) {
                        acc[mt] = (f32x4){0.f, 0.f, 0.f, 0.f};
                        acc[mt] = MFMA(wf[mt], inf, acc[mt]);
                    }
#pragma unroll
                    for (int mt = 0; mt < 4; ++mt) {
                        uint2 o;
                        o.x = cvt2(fmaxf(acc[mt][0], 0.f), fmaxf(acc[mt][1], 0.f));
                        o.y = cvt2(fmaxf(acc[mt][2], 0.f), fmaxf(acc[mt][3], 0.f));
                        *(uint2*)wr[t][mt] = o;
                    }
                }
            }

            // ---- sigma L1 : 64 -> 64, relu
            layer_h64(lw + OFF_S1, lane, rd0, rd1, wr);

            // ---- sigma L2 : 64 -> 16 [f0=sigma-pre, f1..15=geo], raw; zero f16..31
            {
                const bf16x8 w0 = *(const bf16x8*)(lw + OFF_S2 + 0 * 512 + lane * 8);
                const bf16x8 w1 = *(const bf16x8*)(lw + OFF_S2 + 1 * 512 + lane * 8);
#pragma unroll
                for (int t = 0; t < NPT; ++t) {
                    const bf16x8 i0 = *(const bf16x8*)rd0[t];
                    const bf16x8 i1 = *(const bf16x8*)rd1[t];
                    f32x4 acc = (f32x4){0.f, 0.f, 0.f, 0.f};
                    acc = MFMA(w0, i0, acc);
                    acc = MFMA(w1, i1, acc);
                    sig_pre[t] = acc[0];  // valid in lanes 0..15 (feature 0)
                    uint2 o;
                    o.x = cvt2(acc[0], acc[1]);
                    o.y = cvt2(acc[2], acc[3]);
                    *(uint2*)wr[t][0] = o;
                    const uint2 z = {0u, 0u};
                    *(uint2*)wr[t][1] = z;
                }
            }

            // ---- color L0 : feats[0..31] -> 64, relu (bg: views patched at k=16..18)
            {
                bf16x8 wf[4];
#pragma unroll
                for (int b = 0; b < 4; ++b)
                    wf[b] = *(const bf16x8*)(lw + OFF_C0 + b * 512 + lane * 8);
#pragma unroll
                for (int t = 0; t < NPT; ++t) {
                    bf16x8 inf = *(const bf16x8*)rd0[t];
                    if (br == 0 && g == 2) {
                        const float* vp = P.views + (size_t)(p0 + t * 16 + c) * 3;
                        uint4 iv;
                        iv.x = cvt2(vp[0], vp[1]);
                        iv.y = cvt2(vp[2], 0.f);
                        iv.z = 0u; iv.w = 0u;
                        inf = __builtin_bit_cast(bf16x8, iv);
                    }
                    f32x4 acc[4];
#pragma unroll
                    for (int mt = 0; mt < 4; ++mt) {
                        acc[mt] = (f32x4){0.f, 0.f, 0.f, 0.f};
                        acc[mt] = MFMA(wf[mt], inf, acc[mt]);
                    }
#pragma unroll
                    for (int mt = 0; mt < 4; ++mt) {
                        uint2 o;
                        o.x = cvt2(fmaxf(acc[mt][0], 0.f), fmaxf(acc[mt][1], 0.f));
                        o.y = cvt2(fmaxf(acc[mt][2], 0.f), fmaxf(acc[mt][3], 0.f));
                        *(uint2*)wr[t][mt] = o;
                    }
                }
            }

            // ---- color L1, L2 : 64 -> 64, relu
            layer_h64(lw + OFF_C1, lane, rd0, rd1, wr);
            layer_h64(lw + OFF_C2, lane, rd0, rd1, wr);

            // ---- color L3 : 64 -> rgb (features 0..2, lanes 0..15)
            {
                const bf16x8 w0 = *(const bf16x8*)(lw + OFF_C3 + 0 * 512 + lane * 8);
                const bf16x8 w1 = *(const bf16x8*)(lw + OFF_C3 + 1 * 512 + lane * 8);
#pragma unroll
                for (int t = 0; t < NPT; ++t) {
                    const bf16x8 i0 = *(const bf16x8*)rd0[t];
                    const bf16x8 i1 = *(const bf16x8*)rd1[t];
                    f32x4 acc = (f32x4){0.f, 0.f, 0.f, 0.f};
                    acc = MFMA(w0, i0, acc);
                    acc = MFMA(w1, i1, acc);
                    rp[t] = acc[0]; gp[t] = acc[1]; bp[t] = acc[2];
                }
            }

            // ---- branch epilogue: softplus/sigmoid/mask via v_exp/v_log/v_rcp
#pragma unroll
            for (int t = 0; t < NPT; ++t) {
                const float mk = msk[p0 + t * 16 + c];
                const float x  = sig_pre[t];
                const float ex = __expf(x);                         // v_mul + v_exp
                const float sp = (x > 15.f) ? x : 0.69314718f * __log2f(1.f + ex);
                const float sb = sp * mk;
                stot[t] += sb;
                const float sm = sb * mk;
                car[t] += sm * fast_rcp(1.f + __expf(-rp[t]));
                cag[t] += sm * fast_rcp(1.f + __expf(-gp[t]));
                cab[t] += sm * fast_rcp(1.f + __expf(-bp[t]));
            }
        }

        // ---- final blend + store (lanes 0..15 hold the per-point values)
#pragma unroll
        for (int t = 0; t < NPT; ++t) {
            if (lane < 16) {
                const float s   = stot[t] + 1e-9f;
                const float inv = fast_rcp(s);
                float4 o;
                o.x = car[t] * inv; o.y = cag[t] * inv; o.z = cab[t] * inv; o.w = s;
                *(float4*)(P.out + (size_t)(p0 + t * 16 + lane) * 4) = o;
            }
        }
    }
}

extern "C" void kernel_launch(void* const* d_in, const int* in_sizes, int n_in,
                              void* d_out, int out_size, void* d_ws, size_t ws_size,
                              hipStream_t stream) {
    (void)in_sizes; (void)n_in; (void)d_ws; (void)ws_size; (void)out_size;
    Params P;
    P.emb[0] = (const float*)d_in[0];   // embedded_xyz      (bg)
    P.emb[1] = (const float*)d_in[1];   // embedded_xyzt     (fg)
    P.emb[2] = (const float*)d_in[2];   // embedded_xyzt_cam (actor)
    P.views  = (const float*)d_in[3];
    P.mask[0] = (const float*)d_in[4];
    P.mask[1] = (const float*)d_in[5];
    P.mask[2] = (const float*)d_in[6];
    for (int i = 0; i < 21; ++i) P.w[i] = (const float*)d_in[7 + i];
    P.out = (float*)d_out;
    prep_weights<<<108, 256, 0, stream>>>(P);   // 27648 threads, one u32 word each
    nerf_main<<<GRID, BLOCK, 0, stream>>>(P);
}

// Round 4
// 227.649 us; speedup vs baseline: 1.7708x; 1.7708x over previous
//
#include <hip/hip_runtime.h>

typedef unsigned int  uint;
typedef unsigned short ushort;

#define N_PTS  1048576
#define BLOCK  512
#define WAVES  8
#define NPT    2
#define CHUNK  (WAVES * NPT * 16)     // 256 points per block-iteration
#define NCHUNK (N_PTS / CHUNK)        // 4096
#define GRID   1024                   // 4 blocks/CU resident (LDS 128/160 KB)

static_assert(N_PTS % CHUNK == 0, "chunking");
static_assert(NCHUNK % GRID == 0, "grid stride");

typedef __attribute__((ext_vector_type(8))) __bf16  bf16x8;
typedef __attribute__((ext_vector_type(2))) __bf16  bf16x2;
typedef __attribute__((ext_vector_type(4))) float   f32x4;

struct Params {
    const float* emb[3];
    const float* views;
    const float* mask[3];
    const float* w[21];
    float* out;
};

// Pre-arranged bf16 A-fragment weight blob, written by prep_weights each call.
__device__ uint g_wbuf[3 * 9216];

// per-branch weight blob layout (u16 offsets into g_wbuf viewed as ushort*)
#define OFF_S0 0
#define OFF_S1 2048
#define OFF_S2 6144
#define OFF_C0 7168
#define OFF_C1 9216
#define OFF_C2 13312
#define OFF_C3 17408
#define BR_SZ  18432

// f32 pair -> packed bf16x2 (compiler emits v_cvt_pk_bf16_f32, RNE)
__device__ __forceinline__ uint cvt2(float a, float b) {
    bf16x2 v = {(__bf16)a, (__bf16)b};
    return __builtin_bit_cast(uint, v);
}

__device__ __forceinline__ f32x4 MFMA(bf16x8 a, bf16x8 b, f32x4 c) {
    return __builtin_amdgcn_mfma_f32_16x16x32_bf16(a, b, c, 0, 0, 0);
}

__device__ __forceinline__ float fast_rcp(float x) { return __builtin_amdgcn_rcpf(x); }

// Swizzled pointer into a 16x64-bf16 activation tile (2048 B, row stride 128 B).
__device__ __forceinline__ ushort* actp(ushort* buf, int c, int f) {
    int byte = (c << 7) + (f << 1);
    byte ^= (c & 7) << 4;
    return (ushort*)((char*)buf + byte);
}

// weight element fetch with layer-specific remapping (see R1 notes).
__device__ __forceinline__ float wval(int kind, const float* W, int k, int m) {
    switch (kind) {
        default:
        case 0: return W[k * 64 + m];
        case 1: return W[k * 17 + (m == 0 ? 0 : m + 1)];
        case 2: { int r = (k >= 1 && k <= 15) ? (k + 2) : ((k >= 16 && k <= 18) ? (k - 16) : -1);
                  return (r < 0) ? 0.f : W[r * 64 + m]; }
        case 3: { int r = (k >= 1 && k <= 15) ? (k - 1) : -1;
                  return (r < 0) ? 0.f : W[r * 64 + m]; }
        case 4: return (m < 3) ? W[k * 3 + m] : 0.f;
    }
}

// ------------------- prologue: arrange weights as A-fragments -------------------
__global__ void prep_weights(Params P) {
    const int idx = blockIdx.x * 256 + threadIdx.x;   // 0 .. 27647
    const int br  = idx / 9216;
    const int rem = idx - br * 9216;
    int L, q;
    if      (rem < 1024) { L = 0; q = rem;        }
    else if (rem < 3072) { L = 1; q = rem - 1024; }
    else if (rem < 3584) { L = 2; q = rem - 3072; }
    else if (rem < 4608) { L = 3; q = rem - 3584; }
    else if (rem < 6656) { L = 4; q = rem - 4608; }
    else if (rem < 8704) { L = 5; q = rem - 6656; }
    else                 { L = 6; q = rem - 8704; }
    const float* W   = P.w[br * 7 + L];
    const int kk_n   = (L == 0 || L == 3) ? 1 : 2;
    const int kind   = (L == 2) ? 1 : (L == 3) ? (br == 0 ? 2 : 3) : (L == 6) ? 4 : 0;
    const int E  = q * 2;
    const int b  = E >> 9;
    const int ln = (E >> 3) & 63;
    const int e  = E & 7;
    const int mt = b / kk_n;
    const int kk = b - mt * kk_n;
    const int m  = mt * 16 + (ln & 15);
    const int k  = kk * 32 + (ln >> 4) * 8 + e;
    g_wbuf[idx] = cvt2(wval(kind, W, k, m), wval(kind, W, k + 1, m));
}

// hidden 64->64 layer with relu, NPT tiles; weights read straight from global blob
__device__ __forceinline__ void layer_h64(const ushort* lw, int lane,
                                          ushort* const (&rd0)[NPT],
                                          ushort* const (&rd1)[NPT],
                                          ushort* const (&wr)[NPT][4]) {
    bf16x8 wf[8];
#pragma unroll
    for (int b = 0; b < 8; ++b) wf[b] = *(const bf16x8*)(lw + b * 512 + lane * 8);
#pragma unroll
    for (int t = 0; t < NPT; ++t) {
        const bf16x8 i0 = *(const bf16x8*)rd0[t];
        const bf16x8 i1 = *(const bf16x8*)rd1[t];
        f32x4 acc[4];
#pragma unroll
        for (int mt = 0; mt < 4; ++mt) {
            acc[mt] = (f32x4){0.f, 0.f, 0.f, 0.f};
            acc[mt] = MFMA(wf[mt * 2 + 0], i0, acc[mt]);
            acc[mt] = MFMA(wf[mt * 2 + 1], i1, acc[mt]);
        }
#pragma unroll
        for (int mt = 0; mt < 4; ++mt) {
            uint2 o;
            o.x = cvt2(fmaxf(acc[mt][0], 0.f), fmaxf(acc[mt][1], 0.f));
            o.y = cvt2(fmaxf(acc[mt][2], 0.f), fmaxf(acc[mt][3], 0.f));
            *(uint2*)wr[t][mt] = o;
        }
    }
}

__global__ __launch_bounds__(BLOCK, 4) void nerf_main(Params P) {
    __shared__ __align__(16) ushort lds_act[WAVES][NPT][1024]; // 32 KB act tiles only

    const int tid  = threadIdx.x;
    const int wave = tid >> 6;
    const int lane = tid & 63;
    const int c = lane & 15;   // point within tile
    const int g = lane >> 4;   // lane group
    const ushort* gw = (const ushort*)g_wbuf;

    // hoisted swizzled LDS addresses (loop-invariant per lane)
    ushort* rd0[NPT]; ushort* rd1[NPT]; ushort* wr[NPT][4];
#pragma unroll
    for (int t = 0; t < NPT; ++t) {
        ushort* base = lds_act[wave][t];
        rd0[t] = actp(base, c, g * 8);
        rd1[t] = actp(base, c, 32 + g * 8);
#pragma unroll
        for (int mt = 0; mt < 4; ++mt) wr[t][mt] = actp(base, c, mt * 16 + g * 4);
    }

#pragma unroll 1
    for (int ch = blockIdx.x; ch < NCHUNK; ch += gridDim.x) {
        const int p0 = ch * CHUNK + wave * (NPT * 16);

        float stot[NPT], car[NPT], cag[NPT], cab[NPT];
#pragma unroll
        for (int t = 0; t < NPT; ++t) { stot[t] = 0.f; car[t] = 0.f; cag[t] = 0.f; cab[t] = 0.f; }

#pragma unroll 1
        for (int br = 0; br < 3; ++br) {
            const ushort* lw  = gw + br * BR_SZ;
            const float* emb  = P.emb[br];
            const float* msk  = P.mask[br];
            float sig_pre[NPT], rp[NPT], gp[NPT], bp[NPT];

            // ---- sigma L0 : emb(32) -> 64, relu
            {
                bf16x8 wf[4];
#pragma unroll
                for (int b = 0; b < 4; ++b)
                    wf[b] = *(const bf16x8*)(lw + OFF_S0 + b * 512 + lane * 8);
#pragma unroll
                for (int t = 0; t < NPT; ++t) {
                    const float* ep = emb + (size_t)(p0 + t * 16 + c) * 32 + g * 8;
                    const float4 ea = *(const float4*)ep;
                    const float4 eb = *(const float4*)(ep + 4);
                    uint4 iv;
                    iv.x = cvt2(ea.x, ea.y); iv.y = cvt2(ea.z, ea.w);
                    iv.z = cvt2(eb.x, eb.y); iv.w = cvt2(eb.z, eb.w);
                    const bf16x8 inf = __builtin_bit_cast(bf16x8, iv);
                    f32x4 acc[4];
#pragma unroll
                    for (int mt = 0; mt < 4; ++mt) {
                        acc[mt] = (f32x4){0.f, 0.f, 0.f, 0.f};
                        acc[mt] = MFMA(wf[mt], inf, acc[mt]);
                    }
#pragma unroll
                    for (int mt = 0; mt < 4; ++mt) {
                        uint2 o;
                        o.x = cvt2(fmaxf(acc[mt][0], 0.f), fmaxf(acc[mt][1], 0.f));
                        o.y = cvt2(fmaxf(acc[mt][2], 0.f), fmaxf(acc[mt][3], 0.f));
                        *(uint2*)wr[t][mt] = o;
                    }
                }
            }

            // ---- sigma L1 : 64 -> 64, relu
            layer_h64(lw + OFF_S1, lane, rd0, rd1, wr);

            // ---- sigma L2 : 64 -> 16 [f0=sigma-pre, f1..15=geo], raw; zero f16..31
            {
                const bf16x8 w0 = *(const bf16x8*)(lw + OFF_S2 + 0 * 512 + lane * 8);
                const bf16x8 w1 = *(const bf16x8*)(lw + OFF_S2 + 1 * 512 + lane * 8);
#pragma unroll
                for (int t = 0; t < NPT; ++t) {
                    const bf16x8 i0 = *(const bf16x8*)rd0[t];
                    const bf16x8 i1 = *(const bf16x8*)rd1[t];
                    f32x4 acc = (f32x4){0.f, 0.f, 0.f, 0.f};
                    acc = MFMA(w0, i0, acc);
                    acc = MFMA(w1, i1, acc);
                    sig_pre[t] = acc[0];  // valid in lanes 0..15 (feature 0)
                    uint2 o;
                    o.x = cvt2(acc[0], acc[1]);
                    o.y = cvt2(acc[2], acc[3]);
                    *(uint2*)wr[t][0] = o;
                    const uint2 z = {0u, 0u};
                    *(uint2*)wr[t][1] = z;
                }
            }

            // ---- color L0 : feats[0..31] -> 64, relu (bg: views patched at k=16..18)
            {
                bf16x8 wf[4];
#pragma unroll
                for (int b = 0; b < 4; ++b)
                    wf[b] = *(const bf16x8*)(lw + OFF_C0 + b * 512 + lane * 8);
#pragma unroll
                for (int t = 0; t < NPT; ++t) {
                    bf16x8 inf = *(const bf16x8*)rd0[t];
                    if (br == 0 && g == 2) {
                        const float* vp = P.views + (size_t)(p0 + t * 16 + c) * 3;
                        uint4 iv;
                        iv.x = cvt2(vp[0], vp[1]);
                        iv.y = cvt2(vp[2], 0.f);
                        iv.z = 0u; iv.w = 0u;
                        inf = __builtin_bit_cast(bf16x8, iv);
                    }
                    f32x4 acc[4];
#pragma unroll
                    for (int mt = 0; mt < 4; ++mt) {
                        acc[mt] = (f32x4){0.f, 0.f, 0.f, 0.f};
                        acc[mt] = MFMA(wf[mt], inf, acc[mt]);
                    }
#pragma unroll
                    for (int mt = 0; mt < 4; ++mt) {
                        uint2 o;
                        o.x = cvt2(fmaxf(acc[mt][0], 0.f), fmaxf(acc[mt][1], 0.f));
                        o.y = cvt2(fmaxf(acc[mt][2], 0.f), fmaxf(acc[mt][3], 0.f));
                        *(uint2*)wr[t][mt] = o;
                    }
                }
            }

            // ---- color L1, L2 : 64 -> 64, relu
            layer_h64(lw + OFF_C1, lane, rd0, rd1, wr);
            layer_h64(lw + OFF_C2, lane, rd0, rd1, wr);

            // ---- color L3 : 64 -> rgb (features 0..2, lanes 0..15)
            {
                const bf16x8 w0 = *(const bf16x8*)(lw + OFF_C3 + 0 * 512 + lane * 8);
                const bf16x8 w1 = *(const bf16x8*)(lw + OFF_C3 + 1 * 512 + lane * 8);
#pragma unroll
                for (int t = 0; t < NPT; ++t) {
                    const bf16x8 i0 = *(const bf16x8*)rd0[t];
                    const bf16x8 i1 = *(const bf16x8*)rd1[t];
                    f32x4 acc = (f32x4){0.f, 0.f, 0.f, 0.f};
                    acc = MFMA(w0, i0, acc);
                    acc = MFMA(w1, i1, acc);
                    rp[t] = acc[0]; gp[t] = acc[1]; bp[t] = acc[2];
                }
            }

            // ---- branch epilogue: softplus/sigmoid/mask via v_exp/v_log/v_rcp
#pragma unroll
            for (int t = 0; t < NPT; ++t) {
                const float mk = msk[p0 + t * 16 + c];
                const float x  = sig_pre[t];
                const float ex = __expf(x);
                const float sp = (x > 15.f) ? x : 0.69314718f * __log2f(1.f + ex);
                const float sb = sp * mk;
                stot[t] += sb;
                const float sm = sb * mk;
                car[t] += sm * fast_rcp(1.f + __expf(-rp[t]));
                cag[t] += sm * fast_rcp(1.f + __expf(-gp[t]));
                cab[t] += sm * fast_rcp(1.f + __expf(-bp[t]));
            }
        }

        // ---- final blend + store (lanes 0..15 hold the per-point values)
#pragma unroll
        for (int t = 0; t < NPT; ++t) {
            if (lane < 16) {
                const float s   = stot[t] + 1e-9f;
                const float inv = fast_rcp(s);
                float4 o;
                o.x = car[t] * inv; o.y = cag[t] * inv; o.z = cab[t] * inv; o.w = s;
                *(float4*)(P.out + (size_t)(p0 + t * 16 + lane) * 4) = o;
            }
        }
    }
}

extern "C" void kernel_launch(void* const* d_in, const int* in_sizes, int n_in,
                              void* d_out, int out_size, void* d_ws, size_t ws_size,
                              hipStream_t stream) {
    (void)in_sizes; (void)n_in; (void)d_ws; (void)ws_size; (void)out_size;
    Params P;
    P.emb[0] = (const float*)d_in[0];   // embedded_xyz      (bg)
    P.emb[1] = (const float*)d_in[1];   // embedded_xyzt     (fg)
    P.emb[2] = (const float*)d_in[2];   // embedded_xyzt_cam (actor)
    P.views  = (const float*)d_in[3];
    P.mask[0] = (const float*)d_in[4];
    P.mask[1] = (const float*)d_in[5];
    P.mask[2] = (const float*)d_in[6];
    for (int i = 0; i < 21; ++i) P.w[i] = (const float*)d_in[7 + i];
    P.out = (float*)d_out;
    prep_weights<<<108, 256, 0, stream>>>(P);   // 27648 threads, one u32 word each
    nerf_main<<<GRID, BLOCK, 0, stream>>>(P);
}